// Round 1
// 818.973 us; speedup vs baseline: 2.4332x; 2.4332x over previous
//
#include <hip/hip_runtime.h>
#include <hip/hip_bf16.h>
#include <cstdio>

#define N_NODES 50000
#define E_EDGES 1000000
#define FIN 512
#define FOUT 128

__device__ __forceinline__ float bf2f(unsigned short u) {
    unsigned int x = ((unsigned int)u) << 16;
    return __builtin_bit_cast(float, x);
}
__device__ __forceinline__ unsigned short f2bf(float f) {
    unsigned int x = __builtin_bit_cast(unsigned int, f);
    unsigned int r = x + 0x7fffu + ((x >> 16) & 1u);  // RNE
    return (unsigned short)(r >> 16);
}

// managed dump buffer: [0..7] x raw dwords, [8..15] idx0 raw dwords,
// [16] f32flag, [17] i64flag, [24..31] d_out dwords after epilogue
__managed__ unsigned int g_dump[32];

// ---------------------------------------------------------------- dtype detection
__global__ void detect_kernel(const unsigned int* __restrict__ xraw,
                              const unsigned int* __restrict__ idxraw,
                              int* __restrict__ flags) {
    __shared__ int cnt, odd_nz;
    const int t = threadIdx.x;
    if (t == 0) { cnt = 0; odd_nz = 0; }
    __syncthreads();
    int local = 0;
    for (int i = t; i < 1024; i += 256) {
        unsigned int b = (xraw[i] >> 7) & 0xFF;   // bits 14..7 = low-half bf16 exponent field
        if (b >= 115 && b <= 133) local++;
    }
    atomicAdd(&cnt, local);
    if (t < 128) {
        if (idxraw[2 * t + 1] != 0u) atomicAdd(&odd_nz, 1);
    }
    __syncthreads();
    if (t == 0) {
        flags[0] = (cnt < 512) ? 1 : 0;   // 1 => floats are f32
        flags[1] = (odd_nz == 0) ? 1 : 0; // 1 => indices are int64
        g_dump[16] = (unsigned int)flags[0];
        g_dump[17] = (unsigned int)flags[1];
    }
    if (t < 8) {
        g_dump[t]     = xraw[t];
        g_dump[8 + t] = idxraw[t];
    }
}

// ---------------------------------------------------------------- zero helper
__global__ void zero_kernel(float4* __restrict__ p, int n4) {
    int i = blockIdx.x * blockDim.x + threadIdx.x;
    int stride = gridDim.x * blockDim.x;
    for (; i < n4; i += stride) p[i] = make_float4(0.f, 0.f, 0.f, 0.f);
}

// ---------------------------------------------------------------- GEMM (VALU, dtype-adaptive): pre = x @ W, f32 out
__global__ __launch_bounds__(256) void gemm_kernel(const void* __restrict__ xv,
                                                   const void* __restrict__ Wv,
                                                   float* __restrict__ pre,
                                                   const int* __restrict__ flags) {
    __shared__ float sx[8 * FIN];   // 16 KB: 8 staged x-rows as f32

    const int tid = threadIdx.x;
    const int r0  = blockIdx.x * 8;  // 50000 = 8 * 6250 exactly
    const int f32m = flags[0];

    if (f32m) {
        const float4* xp = (const float4*)((const float*)xv + (size_t)r0 * FIN);
#pragma unroll
        for (int j = 0; j < 4; j++)
            ((float4*)sx)[tid * 4 + j] = xp[tid * 4 + j];
    } else {
        const ushort* xh = (const ushort*)xv + (size_t)r0 * FIN;
        const int base = tid * 16;
        ushort tmp[16];
        *(uint4*)(tmp)     = *(const uint4*)(xh + base);
        *(uint4*)(tmp + 8) = *(const uint4*)(xh + base + 8);
#pragma unroll
        for (int i = 0; i < 16; i++) sx[base + i] = bf2f(tmp[i]);
    }
    __syncthreads();

    const int col = tid & 127;
    const int g   = tid >> 7;        // 0 or 1
    float acc[4] = {0.f, 0.f, 0.f, 0.f};

    if (f32m) {
        const float* Wf = (const float*)Wv;
#pragma unroll 4
        for (int k = 0; k < FIN; k++) {
            float w = Wf[(size_t)k * FOUT + col];
#pragma unroll
            for (int j = 0; j < 4; j++)
                acc[j] = fmaf(sx[(4 * g + j) * FIN + k], w, acc[j]);
        }
    } else {
        const ushort* Wh = (const ushort*)Wv;
#pragma unroll 4
        for (int k = 0; k < FIN; k++) {
            float w = bf2f(Wh[(size_t)k * FOUT + col]);
#pragma unroll
            for (int j = 0; j < 4; j++)
                acc[j] = fmaf(sx[(4 * g + j) * FIN + k], w, acc[j]);
        }
    }

#pragma unroll
    for (int j = 0; j < 4; j++) {
        int row = r0 + 4 * g + j;
        pre[(size_t)row * FOUT + col] = acc[j];
    }
}

// ---------------------------------------------------------------- CSR build step 1: histogram of destination rows
__global__ __launch_bounds__(256) void hist_kernel(const void* __restrict__ idx0v,
                                                   const void* __restrict__ idx1v,
                                                   int* __restrict__ cnt0,
                                                   int* __restrict__ cnt1,
                                                   const int* __restrict__ flags) {
    const int i64m = flags[1];
    int i = blockIdx.x * blockDim.x + threadIdx.x;
    const int stride = gridDim.x * blockDim.x;
    const int total = 2 * E_EDGES;
    for (int e = i; e < total; e += stride) {
        const int s  = (e >= E_EDGES);
        const int ee = e - s * E_EDGES;
        const int* idx32 = (const int*)(s ? idx1v : idx0v);
        int row = i64m ? idx32[2 * (size_t)ee] : idx32[ee];
        atomicAdd((s ? cnt1 : cnt0) + row, 1);
    }
}

// ---------------------------------------------------------------- CSR build step 2: exclusive scan (one block per support)
#define SCAN_T 1024
__global__ __launch_bounds__(1024) void scan_kernel(const int* __restrict__ cnt0,
                                                    const int* __restrict__ cnt1,
                                                    int* __restrict__ offs0,
                                                    int* __restrict__ offs1,
                                                    int* __restrict__ cur0,
                                                    int* __restrict__ cur1) {
    __shared__ int part[SCAN_T];
    const int s = blockIdx.x;
    const int* cnt = s ? cnt1 : cnt0;
    int* offs = s ? offs1 : offs0;
    int* cur  = s ? cur1  : cur0;
    const int t = threadIdx.x;
    const int per = (N_NODES + SCAN_T - 1) / SCAN_T;   // 49
    const int base = t * per;
    int sum = 0;
    for (int i = 0; i < per; i++) {
        int idx = base + i;
        if (idx < N_NODES) sum += cnt[idx];
    }
    part[t] = sum;
    __syncthreads();
    for (int d = 1; d < SCAN_T; d <<= 1) {
        int v = (t >= d) ? part[t - d] : 0;
        __syncthreads();
        part[t] += v;
        __syncthreads();
    }
    int run = part[t] - sum;   // exclusive prefix for this thread's chunk
    for (int i = 0; i < per; i++) {
        int idx = base + i;
        if (idx < N_NODES) {
            offs[idx] = run;
            cur[idx]  = run;
            run += cnt[idx];
        }
    }
    if (t == SCAN_T - 1) offs[N_NODES] = part[SCAN_T - 1];
}

// ---------------------------------------------------------------- CSR build step 3: place (col,val) into row segments
__global__ __launch_bounds__(256) void fill_kernel(const void* __restrict__ idx0v, const void* __restrict__ vals0v,
                                                   const void* __restrict__ idx1v, const void* __restrict__ vals1v,
                                                   int* __restrict__ cur0, int* __restrict__ cur1,
                                                   int* __restrict__ col0, float* __restrict__ val0,
                                                   int* __restrict__ col1, float* __restrict__ val1,
                                                   const int* __restrict__ flags) {
    const int i64m = flags[1];
    const int f32m = flags[0];
    int i = blockIdx.x * blockDim.x + threadIdx.x;
    const int stride = gridDim.x * blockDim.x;
    const int total = 2 * E_EDGES;
    for (int e = i; e < total; e += stride) {
        const int s  = (e >= E_EDGES);
        const int ee = e - s * E_EDGES;
        const int* idx32 = (const int*)(s ? idx1v : idx0v);
        const void* valsv = s ? vals1v : vals0v;
        int row, col;
        if (i64m) {
            row = idx32[2 * (size_t)ee];
            col = idx32[2 * ((size_t)E_EDGES + ee)];
        } else {
            row = idx32[ee];
            col = idx32[E_EDGES + ee];
        }
        float v = f32m ? ((const float*)valsv)[ee] : bf2f(((const ushort*)valsv)[ee]);
        int pos = atomicAdd((s ? cur1 : cur0) + row, 1);
        if (s) { col1[pos] = col; val1[pos] = v; }
        else   { col0[pos] = col; val0[pos] = v; }
    }
}

// ---------------------------------------------------------------- gather: one wave per output row, fused bias+relu+store
__global__ __launch_bounds__(256) void gather_kernel(
        const float* __restrict__ pre,
        const int* __restrict__ offs0, const int* __restrict__ col0, const float* __restrict__ val0,
        const int* __restrict__ offs1, const int* __restrict__ col1, const float* __restrict__ val1,
        const void* __restrict__ biasv, void* __restrict__ outv,
        const int* __restrict__ flags) {
    const int w    = (int)((blockIdx.x * blockDim.x + threadIdx.x) >> 6);  // global wave = output row
    const int lane = threadIdx.x & 63;
    if (w >= 2 * N_NODES) return;
    const int s  = (w >= N_NODES);
    const int rr = w - s * N_NODES;
    const int*   offs = s ? offs1 : offs0;
    const int*   colv = s ? col1  : col0;
    const float* valv = s ? val1  : val0;
    const int beg = offs[rr];
    const int end = offs[rr + 1];

    float a0 = 0.f, a1 = 0.f;
    for (int b = beg; b < end; b += 64) {
        const int kk = min(64, end - b);
        int   c = 0;
        float v = 0.f;
        if (lane < kk) { c = colv[b + lane]; v = valv[b + lane]; }
        for (int j = 0; j < kk; j++) {
            const int   cj = __shfl(c, j);
            const float vj = __shfl(v, j);
            const float2 p = *(const float2*)(pre + (size_t)cj * FOUT + lane * 2);
            a0 = fmaf(vj, p.x, a0);
            a1 = fmaf(vj, p.y, a1);
        }
    }

    const int f32m = flags[0];
    float b0, b1;
    if (f32m) {
        const float* bf = (const float*)biasv;
        b0 = bf[lane * 2]; b1 = bf[lane * 2 + 1];
    } else {
        const ushort* bh = (const ushort*)biasv;
        b0 = bf2f(bh[lane * 2]); b1 = bf2f(bh[lane * 2 + 1]);
    }
    const float r0v = fmaxf(a0 + b0, 0.f);
    const float r1v = fmaxf(a1 + b1, 0.f);
    if (f32m) {
        ((float2*)outv)[(size_t)w * 64 + lane] = make_float2(r0v, r1v);
    } else {
        unsigned int o = (unsigned int)f2bf(r0v) | ((unsigned int)f2bf(r1v) << 16);
        ((unsigned int*)outv)[(size_t)w * 64 + lane] = o;
    }
}

// ---------------------------------------------------------------- dump first 8 dwords of out
__global__ void dump_out_kernel(const unsigned int* __restrict__ out) {
    int t = threadIdx.x;
    if (t < 8) g_dump[24 + t] = out[t];
}

static void host_cb(void* ud) {
    (void)ud;
    fprintf(stderr, "[probe] flags: f32=%u i64=%u\n", g_dump[16], g_dump[17]);
    fprintf(stderr, "[probe] x[0..7]:   %08x %08x %08x %08x %08x %08x %08x %08x\n",
            g_dump[0], g_dump[1], g_dump[2], g_dump[3], g_dump[4], g_dump[5], g_dump[6], g_dump[7]);
    fprintf(stderr, "[probe] idx[0..7]: %08x %08x %08x %08x %08x %08x %08x %08x\n",
            g_dump[8], g_dump[9], g_dump[10], g_dump[11], g_dump[12], g_dump[13], g_dump[14], g_dump[15]);
    fprintf(stderr, "[probe] out[0..7]: %08x %08x %08x %08x %08x %08x %08x %08x\n",
            g_dump[24], g_dump[25], g_dump[26], g_dump[27], g_dump[28], g_dump[29], g_dump[30], g_dump[31]);
    fflush(stderr);
}

extern "C" void kernel_launch(void* const* d_in, const int* in_sizes, int n_in,
                              void* d_out, int out_size, void* d_ws, size_t ws_size,
                              hipStream_t stream) {
    (void)in_sizes; (void)n_in; (void)out_size; (void)ws_size;
    const void* x     = d_in[0];   // [N, FIN] f32 or bf16
    const void* idx0  = d_in[1];   // [2, E] int64 or int32
    const void* vals0 = d_in[2];   // [E]
    const void* idx1  = d_in[3];   // [2, E]
    const void* vals1 = d_in[4];   // [E]
    const void* W     = d_in[5];   // [FIN, FOUT]
    const void* bias  = d_in[6];   // [FOUT]

    char* ws = (char*)d_ws;
    const size_t MB = 1024 * 1024;
    // ws layout:
    //   0        : pre f32 [N*FOUT]            (25.6 MB)
    //   32MB     : cnt0, cnt1, offs0, offs1, cur0, cur1  (6 x 256KB slots)
    //   40MB+    : col0 (4MB) | val0 (4MB) | col1 (4MB) | val1 (4MB)
    //   400MB    : flags int[2]
    float* pre   = (float*)ws;
    int* cnt0  = (int*)(ws + 32 * MB);
    int* cnt1  = (int*)(ws + 32 * MB + 256 * 1024);
    int* offs0 = (int*)(ws + 32 * MB + 512 * 1024);
    int* offs1 = (int*)(ws + 32 * MB + 768 * 1024);
    int* cur0  = (int*)(ws + 32 * MB + 1024 * 1024);
    int* cur1  = (int*)(ws + 32 * MB + 1280 * 1024);
    int*   col0 = (int*)(ws + 40 * MB);
    float* val0 = (float*)(ws + 44 * MB);
    int*   col1 = (int*)(ws + 48 * MB);
    float* val1 = (float*)(ws + 52 * MB);
    int* flags = (int*)(ws + 400 * MB);

    detect_kernel<<<dim3(1), dim3(256), 0, stream>>>(
        (const unsigned int*)x, (const unsigned int*)idx0, flags);
    // zero the two count arrays (512 KB region)
    zero_kernel<<<dim3(128), dim3(256), 0, stream>>>((float4*)cnt0, (512 * 1024) / 16);
    gemm_kernel<<<dim3(N_NODES / 8), dim3(256), 0, stream>>>(x, W, pre, flags);
    hist_kernel<<<dim3(2048), dim3(256), 0, stream>>>(idx0, idx1, cnt0, cnt1, flags);
    scan_kernel<<<dim3(2), dim3(SCAN_T), 0, stream>>>(cnt0, cnt1, offs0, offs1, cur0, cur1);
    fill_kernel<<<dim3(2048), dim3(256), 0, stream>>>(idx0, vals0, idx1, vals1,
                                                      cur0, cur1, col0, val0, col1, val1, flags);
    gather_kernel<<<dim3(2 * N_NODES / 4), dim3(256), 0, stream>>>(
        pre, offs0, col0, val0, offs1, col1, val1, bias, d_out, flags);
    dump_out_kernel<<<dim3(1), dim3(64), 0, stream>>>((const unsigned int*)d_out);
    hipLaunchHostFunc(stream, host_cb, nullptr);
}

// Round 4
// 786.916 us; speedup vs baseline: 2.5324x; 1.0407x over previous
//
#include <hip/hip_runtime.h>
#include <hip/hip_bf16.h>

#define N_NODES 50000
#define E_EDGES 1000000
#define FIN 512
#define FOUT 128

__device__ __forceinline__ float bf2f(unsigned short u) {
    unsigned int x = ((unsigned int)u) << 16;
    return __builtin_bit_cast(float, x);
}
__device__ __forceinline__ unsigned short f2bf(float f) {
    unsigned int x = __builtin_bit_cast(unsigned int, f);
    unsigned int r = x + 0x7fffu + ((x >> 16) & 1u);  // RNE
    return (unsigned short)(r >> 16);
}

// ---------------------------------------------------------------- dtype detection
__global__ void detect_kernel(const unsigned int* __restrict__ xraw,
                              const unsigned int* __restrict__ idxraw,
                              int* __restrict__ flags) {
    __shared__ int cnt, odd_nz;
    const int t = threadIdx.x;
    if (t == 0) { cnt = 0; odd_nz = 0; }
    __syncthreads();
    int local = 0;
    for (int i = t; i < 1024; i += 256) {
        unsigned int b = (xraw[i] >> 7) & 0xFF;   // bits 14..7 = low-half bf16 exponent field
        if (b >= 115 && b <= 133) local++;
    }
    atomicAdd(&cnt, local);
    if (t < 128) {
        if (idxraw[2 * t + 1] != 0u) atomicAdd(&odd_nz, 1);
    }
    __syncthreads();
    if (t == 0) {
        flags[0] = (cnt < 512) ? 1 : 0;   // 1 => floats are f32
        flags[1] = (odd_nz == 0) ? 1 : 0; // 1 => indices are int64
    }
}

// ---------------------------------------------------------------- zero helper
__global__ void zero_kernel(float4* __restrict__ p, int n4) {
    int i = blockIdx.x * blockDim.x + threadIdx.x;
    int stride = gridDim.x * blockDim.x;
    for (; i < n4; i += stride) p[i] = make_float4(0.f, 0.f, 0.f, 0.f);
}

// ---------------------------------------------------------------- GEMM: pre = x @ W, 4x4 register-blocked VALU, dtype-adaptive
// Block covers 32 rows x 128 cols; K-tile = 64.
// LDS: sx [32][68] f32 (pad 4 -> per-k row reads hit spread banks), sw [64][128] f32.
#define GBR 32
#define GKT 64
#define SXS 68
__global__ __launch_bounds__(256) void gemm_kernel(const void* __restrict__ xv,
                                                   const void* __restrict__ Wv,
                                                   float* __restrict__ pre,
                                                   const int* __restrict__ flags) {
    __shared__ float sx[GBR * SXS];   // 8.5 KB
    __shared__ float sw[GKT * FOUT];  // 32 KB

    const int tid  = threadIdx.x;
    const int f32m = flags[0];
    const int r0   = blockIdx.x * GBR;

    const int cg  = tid & 31;         // col group -> 4 cols
    const int rg  = tid >> 5;         // row group 0..7 -> 4 rows
    const int c0  = cg * 4;
    const int rl0 = rg * 4;

    // staging coords: each thread loads 8 f32 of x (one row, 8 k) and 32 f32 of W
    const int lrow  = tid >> 3;           // 0..31
    const int kbase = (tid & 7) * 8;      // 0..56
    int grow = r0 + lrow;
    if (grow >= N_NODES) grow = N_NODES - 1;   // clamp; store is guarded

    float acc[4][4];
#pragma unroll
    for (int j = 0; j < 4; j++)
#pragma unroll
        for (int i = 0; i < 4; i++) acc[j][i] = 0.f;

    for (int kt = 0; kt < FIN; kt += GKT) {
        // ---- stage x tile (32 rows x 64 k)
        if (f32m) {
            const float* xf = (const float*)xv + (size_t)grow * FIN + kt + kbase;
            float4 a = ((const float4*)xf)[0];
            float4 b = ((const float4*)xf)[1];
            *(float4*)&sx[lrow * SXS + kbase]     = a;
            *(float4*)&sx[lrow * SXS + kbase + 4] = b;
        } else {
            const ushort* xh = (const ushort*)xv + (size_t)grow * FIN + kt + kbase;
            ushort tmp[8];
            *(uint4*)tmp = *(const uint4*)xh;
#pragma unroll
            for (int j = 0; j < 8; j++) sx[lrow * SXS + kbase + j] = bf2f(tmp[j]);
        }
        // ---- stage W tile (64 k x 128 cols)
        if (f32m) {
            const float4* wf = (const float4*)((const float*)Wv + (size_t)kt * FOUT);
#pragma unroll
            for (int j = 0; j < 8; j++)
                ((float4*)sw)[tid * 8 + j] = wf[tid * 8 + j];
        } else {
            const ushort* wh = (const ushort*)Wv + (size_t)kt * FOUT;
#pragma unroll
            for (int j = 0; j < 4; j++) {
                ushort tmp[8];
                *(uint4*)tmp = *(const uint4*)(wh + tid * 32 + j * 8);
#pragma unroll
                for (int i = 0; i < 8; i++) sw[tid * 32 + j * 8 + i] = bf2f(tmp[i]);
            }
        }
        __syncthreads();

#pragma unroll 4
        for (int k = 0; k < GKT; k++) {
            const float4 w = *(const float4*)&sw[k * FOUT + c0];
            const float x0 = sx[(rl0 + 0) * SXS + k];
            const float x1 = sx[(rl0 + 1) * SXS + k];
            const float x2 = sx[(rl0 + 2) * SXS + k];
            const float x3 = sx[(rl0 + 3) * SXS + k];
            acc[0][0] = fmaf(x0, w.x, acc[0][0]);
            acc[0][1] = fmaf(x0, w.y, acc[0][1]);
            acc[0][2] = fmaf(x0, w.z, acc[0][2]);
            acc[0][3] = fmaf(x0, w.w, acc[0][3]);
            acc[1][0] = fmaf(x1, w.x, acc[1][0]);
            acc[1][1] = fmaf(x1, w.y, acc[1][1]);
            acc[1][2] = fmaf(x1, w.z, acc[1][2]);
            acc[1][3] = fmaf(x1, w.w, acc[1][3]);
            acc[2][0] = fmaf(x2, w.x, acc[2][0]);
            acc[2][1] = fmaf(x2, w.y, acc[2][1]);
            acc[2][2] = fmaf(x2, w.z, acc[2][2]);
            acc[2][3] = fmaf(x2, w.w, acc[2][3]);
            acc[3][0] = fmaf(x3, w.x, acc[3][0]);
            acc[3][1] = fmaf(x3, w.y, acc[3][1]);
            acc[3][2] = fmaf(x3, w.z, acc[3][2]);
            acc[3][3] = fmaf(x3, w.w, acc[3][3]);
        }
        __syncthreads();
    }

#pragma unroll
    for (int j = 0; j < 4; j++) {
        const int row = r0 + rl0 + j;
        if (row < N_NODES) {
            float4 o = make_float4(acc[j][0], acc[j][1], acc[j][2], acc[j][3]);
            *(float4*)&pre[(size_t)row * FOUT + c0] = o;
        }
    }
}

// ---------------------------------------------------------------- CSR build step 1: histogram of destination rows
__global__ __launch_bounds__(256) void hist_kernel(const void* __restrict__ idx0v,
                                                   const void* __restrict__ idx1v,
                                                   int* __restrict__ cnt0,
                                                   int* __restrict__ cnt1,
                                                   const int* __restrict__ flags) {
    const int i64m = flags[1];
    int i = blockIdx.x * blockDim.x + threadIdx.x;
    const int stride = gridDim.x * blockDim.x;
    const int total = 2 * E_EDGES;
    for (int e = i; e < total; e += stride) {
        const int s  = (e >= E_EDGES);
        const int ee = e - s * E_EDGES;
        const int* idx32 = (const int*)(s ? idx1v : idx0v);
        int row = i64m ? idx32[2 * (size_t)ee] : idx32[ee];
        atomicAdd((s ? cnt1 : cnt0) + row, 1);
    }
}

// ---------------------------------------------------------------- CSR build step 2: exclusive scan (one block per support)
#define SCAN_T 1024
__global__ __launch_bounds__(1024) void scan_kernel(const int* __restrict__ cnt0,
                                                    const int* __restrict__ cnt1,
                                                    int* __restrict__ offs0,
                                                    int* __restrict__ offs1,
                                                    int* __restrict__ cur0,
                                                    int* __restrict__ cur1) {
    __shared__ int part[SCAN_T];
    const int s = blockIdx.x;
    const int* cnt = s ? cnt1 : cnt0;
    int* offs = s ? offs1 : offs0;
    int* cur  = s ? cur1  : cur0;
    const int t = threadIdx.x;
    const int per = (N_NODES + SCAN_T - 1) / SCAN_T;   // 49
    const int base = t * per;
    int sum = 0;
    for (int i = 0; i < per; i++) {
        int idx = base + i;
        if (idx < N_NODES) sum += cnt[idx];
    }
    part[t] = sum;
    __syncthreads();
    for (int d = 1; d < SCAN_T; d <<= 1) {
        int v = (t >= d) ? part[t - d] : 0;
        __syncthreads();
        part[t] += v;
        __syncthreads();
    }
    int run = part[t] - sum;   // exclusive prefix for this thread's chunk
    for (int i = 0; i < per; i++) {
        int idx = base + i;
        if (idx < N_NODES) {
            offs[idx] = run;
            cur[idx]  = run;
            run += cnt[idx];
        }
    }
    if (t == SCAN_T - 1) offs[N_NODES] = part[SCAN_T - 1];
}

// ---------------------------------------------------------------- CSR build step 3: place {col,val} pairs into row segments
__global__ __launch_bounds__(256) void fill_kernel(const void* __restrict__ idx0v, const void* __restrict__ vals0v,
                                                   const void* __restrict__ idx1v, const void* __restrict__ vals1v,
                                                   int* __restrict__ cur0, int* __restrict__ cur1,
                                                   int2* __restrict__ pair0, int2* __restrict__ pair1,
                                                   const int* __restrict__ flags) {
    const int i64m = flags[1];
    const int f32m = flags[0];
    int i = blockIdx.x * blockDim.x + threadIdx.x;
    const int stride = gridDim.x * blockDim.x;
    const int total = 2 * E_EDGES;
    for (int e = i; e < total; e += stride) {
        const int s  = (e >= E_EDGES);
        const int ee = e - s * E_EDGES;
        const int* idx32 = (const int*)(s ? idx1v : idx0v);
        const void* valsv = s ? vals1v : vals0v;
        int row, col;
        if (i64m) {
            row = idx32[2 * (size_t)ee];
            col = idx32[2 * ((size_t)E_EDGES + ee)];
        } else {
            row = idx32[ee];
            col = idx32[E_EDGES + ee];
        }
        float v = f32m ? ((const float*)valsv)[ee] : bf2f(((const ushort*)valsv)[ee]);
        int pos = atomicAdd((s ? cur1 : cur0) + row, 1);
        int2 pr;
        pr.x = col;
        pr.y = __float_as_int(v);
        (s ? pair1 : pair0)[pos] = pr;
    }
}

// ---------------------------------------------------------------- gather: one wave per output row, fused bias+relu+store
__global__ __launch_bounds__(256) void gather_kernel(
        const float* __restrict__ pre,
        const int* __restrict__ offs0, const int2* __restrict__ pair0,
        const int* __restrict__ offs1, const int2* __restrict__ pair1,
        const void* __restrict__ biasv, void* __restrict__ outv,
        const int* __restrict__ flags) {
    const int w    = (int)((blockIdx.x * blockDim.x + threadIdx.x) >> 6);  // global wave = output row
    const int lane = threadIdx.x & 63;
    if (w >= 2 * N_NODES) return;
    const int s  = (w >= N_NODES);
    const int rr = w - s * N_NODES;
    const int*  offs  = s ? offs1 : offs0;
    const int2* pairs = s ? pair1 : pair0;
    const int beg = offs[rr];
    const int end = offs[rr + 1];

    float a0 = 0.f, a1 = 0.f;
    for (int b = beg; b < end; b += 64) {
        const int kk = min(64, end - b);
        int2 pr; pr.x = 0; pr.y = 0;
        if (lane < kk) pr = pairs[b + lane];
        for (int j = 0; j < kk; j++) {
            const int   cj = __shfl(pr.x, j);
            const float vj = __int_as_float(__shfl(pr.y, j));
            const float2 p = *(const float2*)(pre + (size_t)cj * FOUT + lane * 2);
            a0 = fmaf(vj, p.x, a0);
            a1 = fmaf(vj, p.y, a1);
        }
    }

    const int f32m = flags[0];
    float b0, b1;
    if (f32m) {
        const float* bf = (const float*)biasv;
        b0 = bf[lane * 2]; b1 = bf[lane * 2 + 1];
    } else {
        const ushort* bh = (const ushort*)biasv;
        b0 = bf2f(bh[lane * 2]); b1 = bf2f(bh[lane * 2 + 1]);
    }
    const float r0v = fmaxf(a0 + b0, 0.f);
    const float r1v = fmaxf(a1 + b1, 0.f);
    if (f32m) {
        ((float2*)outv)[(size_t)w * 64 + lane] = make_float2(r0v, r1v);
    } else {
        unsigned int o = (unsigned int)f2bf(r0v) | ((unsigned int)f2bf(r1v) << 16);
        ((unsigned int*)outv)[(size_t)w * 64 + lane] = o;
    }
}

extern "C" void kernel_launch(void* const* d_in, const int* in_sizes, int n_in,
                              void* d_out, int out_size, void* d_ws, size_t ws_size,
                              hipStream_t stream) {
    (void)in_sizes; (void)n_in; (void)out_size; (void)ws_size;
    const void* x     = d_in[0];   // [N, FIN] f32 or bf16
    const void* idx0  = d_in[1];   // [2, E] int64 or int32
    const void* vals0 = d_in[2];   // [E]
    const void* idx1  = d_in[3];   // [2, E]
    const void* vals1 = d_in[4];   // [E]
    const void* W     = d_in[5];   // [FIN, FOUT]
    const void* bias  = d_in[6];   // [FOUT]

    char* ws = (char*)d_ws;
    const size_t MB = 1024 * 1024;
    // ws layout:
    //   0        : pre f32 [N*FOUT]            (25.6 MB)
    //   32MB     : cnt0, cnt1, offs0, offs1, cur0, cur1  (6 x 256KB slots)
    //   40MB     : pair0 int2[E] (8 MB)
    //   48MB     : pair1 int2[E] (8 MB)
    //   400MB    : flags int[2]
    float* pre   = (float*)ws;
    int* cnt0  = (int*)(ws + 32 * MB);
    int* cnt1  = (int*)(ws + 32 * MB + 256 * 1024);
    int* offs0 = (int*)(ws + 32 * MB + 512 * 1024);
    int* offs1 = (int*)(ws + 32 * MB + 768 * 1024);
    int* cur0  = (int*)(ws + 32 * MB + 1024 * 1024);
    int* cur1  = (int*)(ws + 32 * MB + 1280 * 1024);
    int2* pair0 = (int2*)(ws + 40 * MB);
    int2* pair1 = (int2*)(ws + 48 * MB);
    int* flags = (int*)(ws + 400 * MB);

    detect_kernel<<<dim3(1), dim3(256), 0, stream>>>(
        (const unsigned int*)x, (const unsigned int*)idx0, flags);
    // zero the two count arrays (512 KB region)
    zero_kernel<<<dim3(128), dim3(256), 0, stream>>>((float4*)cnt0, (512 * 1024) / 16);
    gemm_kernel<<<dim3((N_NODES + GBR - 1) / GBR), dim3(256), 0, stream>>>(x, W, pre, flags);
    hist_kernel<<<dim3(2048), dim3(256), 0, stream>>>(idx0, idx1, cnt0, cnt1, flags);
    scan_kernel<<<dim3(2), dim3(SCAN_T), 0, stream>>>(cnt0, cnt1, offs0, offs1, cur0, cur1);
    fill_kernel<<<dim3(2048), dim3(256), 0, stream>>>(idx0, vals0, idx1, vals1,
                                                      cur0, cur1, pair0, pair1, flags);
    gather_kernel<<<dim3(2 * N_NODES / 4), dim3(256), 0, stream>>>(
        pre, offs0, pair0, offs1, pair1, bias, d_out, flags);
}